// Round 6
// baseline (272.103 us; speedup 1.0000x reference)
//
#include <hip/hip_runtime.h>
#include <math.h>

typedef _Float16 h2 __attribute__((ext_vector_type(2)));
typedef _Float16 f16x8 __attribute__((ext_vector_type(8)));
typedef float f32x4 __attribute__((ext_vector_type(4)));

// ws layout (floats):
//   [0, 24576)     T tables [3][64][128] f32 (b0 folded into axis 0)
//   [24576, 40960) W1n [128][128] f32 (weight-normed)
//   [40960, 41088) w2n [128] f32 (weight-normed row * g2)

__global__ void precompute_T(const float* __restrict__ expr,
                             const float* __restrict__ jqw,
                             const float* __restrict__ flx,
                             const float* __restrict__ fly,
                             const float* __restrict__ flz,
                             const float* __restrict__ w0v,
                             const float* __restrict__ w0g,
                             const float* __restrict__ b0,
                             float* __restrict__ T) {
    int a = blockIdx.x >> 6;   // axis 0..2
    int l = blockIdx.x & 63;   // grid row 0..63
    const float* fl = (a == 0) ? flx : (a == 1) ? fly : flz;
    __shared__ float bs[32];
    __shared__ float jaw[32];
    int t = threadIdx.x;
    if (t < 32) {
        float s = 0.f;
        for (int i = 0; i < 80; ++i) s += expr[i] * fl[(i * 64 + l) * 32 + t];
        bs[t] = s;
    } else if (t < 64) {
        int c = t - 32;
        float s = 0.f;
        for (int i = 0; i < 16; ++i) s += jqw[i] * fl[((80 + i) * 64 + l) * 32 + c];
        jaw[c] = s;
    }
    __syncthreads();
    int j = t;  // 128 threads, one output channel each
    float ns = 0.f;
    for (int c = 0; c < 192; ++c) { float v = w0v[j * 192 + c]; ns += v * v; }
    float scale = w0g[j] / sqrtf(ns);
    float acc = 0.f;
    for (int c = 0; c < 32; ++c) acc += w0v[j * 192 + a * 32 + c] * bs[c];
    for (int c = 0; c < 32; ++c) acc += w0v[j * 192 + 96 + a * 32 + c] * jaw[c];
    acc *= scale;
    if (a == 0) acc += b0[j];
    T[(a * 64 + l) * 128 + j] = acc;
}

__global__ void precompute_W(const float* __restrict__ w1v,
                             const float* __restrict__ w1g,
                             const float* __restrict__ w2v,
                             const float* __restrict__ w2g,
                             float* __restrict__ W1n,
                             float* __restrict__ w2n) {
    int j = threadIdx.x;  // 128 threads
    float ns = 0.f;
    for (int k = 0; k < 128; ++k) { float v = w1v[j * 128 + k]; ns += v * v; }
    float s = w1g[j] / sqrtf(ns);
    for (int k = 0; k < 128; ++k) W1n[j * 128 + k] = w1v[j * 128 + k] * s;
    float n2 = 0.f;
    for (int k = 0; k < 128; ++k) { float v = w2v[k]; n2 += v * v; }
    w2n[j] = w2v[j] * (w2g[0] / sqrtf(n2));
}

#define LDS_T_H2 12288   // 3*64*128 f16 = 48 KiB (only LDS user now)

// f32 rotation-add within the 16-lane DPP row (pure VALU, off the LDS pipe)
template <int CTRL>
static __device__ __forceinline__ float dpp_ror_add(float x) {
    int yi = __builtin_amdgcn_update_dpp(0, __builtin_bit_cast(int, x),
                                         CTRL, 0xF, 0xF, false);
    return x + __builtin_bit_cast(float, yi);
}

// Each wave: 16-point tiles via v_mfma_f32_16x16x32_f16.
//   A[m][k]: m = point (lane&15), lane holds k = (lane>>4)*8+0..7 per K-step.
//   B[k][n]: W1n^T held ENTIRELY in registers (128 VGPR), loaded once from L2.
//   C[m][n]: m = (lane>>4)*4+i, n = lane&15 (per N-tile).
__launch_bounds__(512)
__attribute__((amdgpu_waves_per_eu(2)))   // 256-VGPR budget: Bf must not spill
__global__ void mlp_mfma(const float* __restrict__ xyz,
                         const float* __restrict__ Tg,
                         const float* __restrict__ W1g,
                         const float* __restrict__ w2ng,
                         const float* __restrict__ b1,
                         const float* __restrict__ b2p,
                         float* __restrict__ out, int npts) {
    __shared__ __align__(16) h2 tT[LDS_T_H2];
    int tid = threadIdx.x;

    // Stage T (f32 -> f16). Row r = 256B = 16 chunks of 16B; chunk c stored at
    // c ^ (r&15): data-dependent row gather (fixed chunk, random row) spreads
    // across 16 chunk slots -> ~2-way bank aliasing.
    for (int pi = tid; pi < LDS_T_H2; pi += 512) {
        int r = pi >> 6;        // row 0..191
        int p = pi & 63;        // h2 within row
        int phys = (r << 6) | (((p >> 2) ^ (r & 15)) << 2) | (p & 3);
        h2 v;
        v.x = (_Float16)Tg[2 * pi];
        v.y = (_Float16)Tg[2 * pi + 1];
        tT[phys] = v;
    }
    __syncthreads();

    int lane = tid & 63;
    int lp = lane & 15;   // point-within-tile (A rows / C cols)
    int lg = lane >> 4;   // k-chunk group

    // W1 B-fragments in registers: Bf[kk][nt][j] = W1n^T[k=kk*32+lg*8+j][n=nt*16+lp]
    f16x8 Bf[4][8];
#pragma unroll
    for (int kk = 0; kk < 4; ++kk) {
#pragma unroll
        for (int nt = 0; nt < 8; ++nt) {
            const float* src = &W1g[(nt * 16 + lp) * 128 + kk * 32 + lg * 8];
            f16x8 b;
#pragma unroll
            for (int j = 0; j < 8; ++j) b[j] = (_Float16)src[j];
            Bf[kk][nt] = b;
        }
    }

    // per-lane epilogue constants: channels n = nt*16 + lp
    float b1r[8], w2r[8];
#pragma unroll
    for (int nt = 0; nt < 8; ++nt) {
        b1r[nt] = b1[nt * 16 + lp];
        w2r[nt] = w2ng[nt * 16 + lp];
    }
    float b2 = b2p[0];

    int waveid = blockIdx.x * 8 + (tid >> 6);
    int nwaves = gridDim.x * 8;
    int ntiles = (npts + 15) >> 4;

#pragma unroll 1
    for (int tile = waveid; tile < ntiles; tile += nwaves) {
        int m0 = tile << 4;
        int p = m0 + lp;
        int pc = min(p, npts - 1);
        float cx = xyz[pc * 3 + 0];
        float cy = xyz[pc * 3 + 1];
        float cz = xyz[pc * 3 + 2];

        // Build A fragments: hA[kk] = relu(h0[point lp][kk*32 + lg*8 + 0..7])
        f16x8 hA[4];
#pragma unroll
        for (int kk = 0; kk < 4; ++kk)
            hA[kk] = (f16x8){0, 0, 0, 0, 0, 0, 0, 0};

#pragma unroll
        for (int a = 0; a < 3; ++a) {
            float v = (a == 0) ? cx : (a == 1) ? cy : cz;
            v = fminf(fmaxf(v, 0.f), 1.f) * 63.f;
            float fv = floorf(v);
            int li = (int)fv;
            int ri = min(li + 1, 63);
            _Float16 w = (_Float16)(v - fv);
            _Float16 wl = (_Float16)1.0f - w;
            f16x8 w8  = {w, w, w, w, w, w, w, w};
            f16x8 wl8 = {wl, wl, wl, wl, wl, wl, wl, wl};
            int rowL = (a * 64 + li) << 4;  // chunk base
            int rowR = (a * 64 + ri) << 4;
            int sl = li & 15;
            int sr = ri & 15;
#pragma unroll
            for (int kk = 0; kk < 4; ++kk) {
                int cidx = lg + 4 * kk;
                f16x8 vl = *reinterpret_cast<const f16x8*>(
                    &tT[(rowL + (cidx ^ sl)) << 2]);
                f16x8 vr = *reinterpret_cast<const f16x8*>(
                    &tT[(rowR + (cidx ^ sr)) << 2]);
                hA[kk] = hA[kk] + vl * wl8 + vr * w8;
            }
        }
        f16x8 z8 = (f16x8){0, 0, 0, 0, 0, 0, 0, 0};
#pragma unroll
        for (int kk = 0; kk < 4; ++kk)
            hA[kk] = __builtin_elementwise_max(hA[kk], z8);

        // Layer 1: 8 N-tiles x 4 K-steps, B straight from registers
        f32x4 acc[8];
#pragma unroll
        for (int nt = 0; nt < 8; ++nt) acc[nt] = (f32x4){0.f, 0.f, 0.f, 0.f};

#pragma unroll
        for (int kk = 0; kk < 4; ++kk) {
#pragma unroll
            for (int nt = 0; nt < 8; ++nt) {
                acc[nt] = __builtin_amdgcn_mfma_f32_16x16x32_f16(
                    hA[kk], Bf[kk][nt], acc[nt], 0, 0, 0);
            }
        }

        // Layer 2 + bias/relu epilogue. acc[nt][i] = h1pre[m=lg*4+i][n=nt*16+lp]
        float part0 = 0.f, part1 = 0.f, part2 = 0.f, part3 = 0.f;
#pragma unroll
        for (int nt = 0; nt < 8; ++nt) {
            part0 += w2r[nt] * fmaxf(acc[nt][0] + b1r[nt], 0.f);
            part1 += w2r[nt] * fmaxf(acc[nt][1] + b1r[nt], 0.f);
            part2 += w2r[nt] * fmaxf(acc[nt][2] + b1r[nt], 0.f);
            part3 += w2r[nt] * fmaxf(acc[nt][3] + b1r[nt], 0.f);
        }
        // reduce over the 16-lane DPP row (channels) via rotation-adds (VALU)
        part0 = dpp_ror_add<0x128>(part0);  // ROW_ROR:8
        part1 = dpp_ror_add<0x128>(part1);
        part2 = dpp_ror_add<0x128>(part2);
        part3 = dpp_ror_add<0x128>(part3);
        part0 = dpp_ror_add<0x124>(part0);  // ROW_ROR:4
        part1 = dpp_ror_add<0x124>(part1);
        part2 = dpp_ror_add<0x124>(part2);
        part3 = dpp_ror_add<0x124>(part3);
        part0 = dpp_ror_add<0x122>(part0);  // ROW_ROR:2
        part1 = dpp_ror_add<0x122>(part1);
        part2 = dpp_ror_add<0x122>(part2);
        part3 = dpp_ror_add<0x122>(part3);
        part0 = dpp_ror_add<0x121>(part0);  // ROW_ROR:1
        part1 = dpp_ror_add<0x121>(part1);
        part2 = dpp_ror_add<0x121>(part2);
        part3 = dpp_ror_add<0x121>(part3);

        int mbase = m0 + (lg << 2);
        if (lp == 0 && mbase + 0 < npts) out[mbase + 0] = part0 + b2;
        if (lp == 1 && mbase + 1 < npts) out[mbase + 1] = part1 + b2;
        if (lp == 2 && mbase + 2 < npts) out[mbase + 2] = part2 + b2;
        if (lp == 3 && mbase + 3 < npts) out[mbase + 3] = part3 + b2;
    }
}

extern "C" void kernel_launch(void* const* d_in, const int* in_sizes, int n_in,
                              void* d_out, int out_size, void* d_ws, size_t ws_size,
                              hipStream_t stream) {
    const float* expr = (const float*)d_in[0];
    const float* jqw  = (const float*)d_in[1];
    const float* xyz  = (const float*)d_in[2];
    const float* flx  = (const float*)d_in[3];
    const float* fly  = (const float*)d_in[4];
    const float* flz  = (const float*)d_in[5];
    const float* w0v  = (const float*)d_in[6];
    const float* w0g  = (const float*)d_in[7];
    const float* b0   = (const float*)d_in[8];
    const float* w1v  = (const float*)d_in[9];
    const float* w1g  = (const float*)d_in[10];
    const float* b1   = (const float*)d_in[11];
    const float* w2v  = (const float*)d_in[12];
    const float* w2g  = (const float*)d_in[13];
    const float* b2   = (const float*)d_in[14];

    float* ws = (float*)d_ws;
    float* T   = ws;            // 24576 floats
    float* W1n = ws + 24576;    // 16384 floats
    float* w2n = ws + 40960;    // 128 floats

    int npts = in_sizes[2] / 3;

    precompute_T<<<192, 128, 0, stream>>>(expr, jqw, flx, fly, flz, w0v, w0g, b0, T);
    precompute_W<<<1, 128, 0, stream>>>(w1v, w1g, w2v, w2g, W1n, w2n);
    mlp_mfma<<<512, 512, 0, stream>>>(xyz, T, W1n, w2n, b1, b2, (float*)d_out, npts);
}

// Round 8
// 235.601 us; speedup vs baseline: 1.1549x; 1.1549x over previous
//
#include <hip/hip_runtime.h>
#include <math.h>

typedef _Float16 h2 __attribute__((ext_vector_type(2)));
typedef _Float16 f16x8 __attribute__((ext_vector_type(8)));
typedef float f32x4 __attribute__((ext_vector_type(4)));

// ws layout (floats):
//   [0, 24576)       T [3][64][128] f32 (b0 folded into axis 0)
//   [24576, 24704)   w0scale[128]
//   [24704, 24832)   w2n[128]
//   [24832, 33024)   Wf: W1n^T f16 B-fragments, 8192 h2
//                    Wf[(f*64+lane)*4+jp] = {W1n[n][k], W1n[n][k+1]},
//                    f=kk*8+nt, n=nt*16+(lane&15), k=kk*32+(lane>>4)*8+2*jp

// One block, 512 threads: all weight-norm scales + f16 fragment-ordered W1.
__global__ void precompute_ws(const float* __restrict__ w0v,
                              const float* __restrict__ w0g,
                              const float* __restrict__ w1v,
                              const float* __restrict__ w1g,
                              const float* __restrict__ w2v,
                              const float* __restrict__ w2g,
                              float* __restrict__ w0scale,
                              float* __restrict__ w2n,
                              h2* __restrict__ Wf) {
    __shared__ float s1[128];
    int t = threadIdx.x;
    if (t < 128) {
        float ns = 0.f;
        for (int c = 0; c < 192; ++c) { float v = w0v[t * 192 + c]; ns += v * v; }
        w0scale[t] = w0g[t] / sqrtf(ns);
        float n1 = 0.f;
        for (int k = 0; k < 128; ++k) { float v = w1v[t * 128 + k]; n1 += v * v; }
        s1[t] = w1g[t] / sqrtf(n1);
        float n2 = 0.f;
        for (int k = 0; k < 128; ++k) { float v = w2v[k]; n2 += v * v; }
        w2n[t] = w2v[t] * (w2g[0] / sqrtf(n2));
    }
    __syncthreads();
    for (int pi = t; pi < 8192; pi += 512) {
        int jp = pi & 3;
        int lane = (pi >> 2) & 63;
        int f = pi >> 8;
        int kk = f >> 3, nt = f & 7;
        int n = nt * 16 + (lane & 15);
        int k = kk * 32 + (lane >> 4) * 8 + jp * 2;
        float s = s1[n];
        h2 v;
        v.x = (_Float16)(w1v[n * 128 + k] * s);
        v.y = (_Float16)(w1v[n * 128 + k + 1] * s);
        Wf[pi] = v;
    }
}

__global__ void precompute_T(const float* __restrict__ expr,
                             const float* __restrict__ jqw,
                             const float* __restrict__ flx,
                             const float* __restrict__ fly,
                             const float* __restrict__ flz,
                             const float* __restrict__ w0v,
                             const float* __restrict__ w0scale,
                             const float* __restrict__ b0,
                             float* __restrict__ T) {
    int a = blockIdx.x >> 6;   // axis 0..2
    int l = blockIdx.x & 63;   // grid row 0..63
    const float* fl = (a == 0) ? flx : (a == 1) ? fly : flz;
    __shared__ float bs[32];
    __shared__ float jaw[32];
    int t = threadIdx.x;
    if (t < 32) {
        float s = 0.f;
        for (int i = 0; i < 80; ++i) s += expr[i] * fl[(i * 64 + l) * 32 + t];
        bs[t] = s;
    } else if (t < 64) {
        int c = t - 32;
        float s = 0.f;
        for (int i = 0; i < 16; ++i) s += jqw[i] * fl[((80 + i) * 64 + l) * 32 + c];
        jaw[c] = s;
    }
    __syncthreads();
    int j = t;  // 128 threads, one output channel each
    float acc = 0.f;
    for (int c = 0; c < 32; ++c) acc += w0v[j * 192 + a * 32 + c] * bs[c];
    for (int c = 0; c < 32; ++c) acc += w0v[j * 192 + 96 + a * 32 + c] * jaw[c];
    acc *= w0scale[j];
    if (a == 0) acc += b0[j];
    T[(a * 64 + l) * 128 + j] = acc;
}

// T in LDS with rows padded to 17 chunks of 16B (272 B): bank-group of
// (row r, chunk c) = (r*17+c) mod 8 = (r+c) mod 8 -> random rows spread
// across all bank groups (row stride no longer 0 mod 128 B).
#define T_ROW_CHUNKS 17
#define LDS_T_H2 (192 * T_ROW_CHUNKS * 4)   // 13056 h2 = 52224 B

// f32 rotation-add within the 16-lane DPP row (pure VALU, off the LDS pipe)
template <int CTRL>
static __device__ __forceinline__ float dpp_ror_add(float x) {
    int yi = __builtin_amdgcn_update_dpp(0, __builtin_bit_cast(int, x),
                                         CTRL, 0xF, 0xF, false);
    return x + __builtin_bit_cast(float, yi);
}

// Each wave: 16-point tiles via v_mfma_f32_16x16x32_f16.
//   A[m][k]: m = point (lane&15), lane holds k = (lane>>4)*8+0..7 per K-step.
//   B[k][n]: W1n^T in registers (128 VGPR), pinned by opaque asm barriers.
//   C[m][n]: m = (lane>>4)*4+i, n = lane&15 (per N-tile).
__launch_bounds__(512)
__attribute__((amdgpu_waves_per_eu(2)))   // 256-VGPR budget for Bf
__global__ void mlp_mfma(const float* __restrict__ xyz,
                         const float* __restrict__ Tg,
                         const f32x4* __restrict__ Wfrag,
                         const float* __restrict__ w2ng,
                         const float* __restrict__ b1,
                         const float* __restrict__ b2p,
                         float* __restrict__ out, int npts) {
    __shared__ __align__(16) h2 tT[LDS_T_H2];
    int tid = threadIdx.x;

    // Stage T (f32 -> f16) into the padded layout.
    for (int pi = tid; pi < 12288; pi += 512) {
        int r = pi >> 6;        // row 0..191
        int p = pi & 63;        // h2 pair within row
        int dst = (r * T_ROW_CHUNKS + (p >> 2)) * 4 + (p & 3);
        h2 v;
        v.x = (_Float16)Tg[2 * pi];
        v.y = (_Float16)Tg[2 * pi + 1];
        tT[dst] = v;
    }
    __syncthreads();

    int lane = tid & 63;
    int lp = lane & 15;   // point-within-tile (A rows / C cols)
    int lg = lane >> 4;   // k-chunk group

    // B-fragments: one coalesced 16B load per fragment, then opaque barrier
    // so the compiler can neither rematerialize nor sink the loads.
    f32x4 Bf[4][8];
#pragma unroll
    for (int kk = 0; kk < 4; ++kk)
#pragma unroll
        for (int nt = 0; nt < 8; ++nt)
            Bf[kk][nt] = Wfrag[(((kk * 8 + nt) << 6) | lane)];
#pragma unroll
    for (int kk = 0; kk < 4; ++kk)
#pragma unroll
        for (int nt = 0; nt < 8; ++nt)
            asm volatile("" : "+v"(Bf[kk][nt]));

    // per-lane epilogue constants: channels n = nt*16 + lp
    float b1r[8], w2r[8];
#pragma unroll
    for (int nt = 0; nt < 8; ++nt) {
        b1r[nt] = b1[nt * 16 + lp];
        w2r[nt] = w2ng[nt * 16 + lp];
    }
    float b2 = b2p[0];

    int waveid = blockIdx.x * 8 + (tid >> 6);
    int nwaves = gridDim.x * 8;
    int ntiles = (npts + 15) >> 4;

#pragma unroll 1
    for (int tile = waveid; tile < ntiles; tile += nwaves) {
        int m0 = tile << 4;
        int p = m0 + lp;
        int pc = min(p, npts - 1);
        float cx = xyz[pc * 3 + 0];
        float cy = xyz[pc * 3 + 1];
        float cz = xyz[pc * 3 + 2];

        // Build A fragments: hA[kk] = relu(h0[point lp][kk*32 + lg*8 + 0..7])
        f16x8 hA[4];
#pragma unroll
        for (int kk = 0; kk < 4; ++kk)
            hA[kk] = (f16x8){0, 0, 0, 0, 0, 0, 0, 0};

#pragma unroll
        for (int a = 0; a < 3; ++a) {
            float v = (a == 0) ? cx : (a == 1) ? cy : cz;
            v = fminf(fmaxf(v, 0.f), 1.f) * 63.f;
            float fv = floorf(v);
            int li = (int)fv;
            int ri = min(li + 1, 63);
            _Float16 w = (_Float16)(v - fv);
            _Float16 wl = (_Float16)1.0f - w;
            f16x8 w8  = {w, w, w, w, w, w, w, w};
            f16x8 wl8 = {wl, wl, wl, wl, wl, wl, wl, wl};
            int cbL = (a * 64 + li) * T_ROW_CHUNKS;
            int cbR = (a * 64 + ri) * T_ROW_CHUNKS;
#pragma unroll
            for (int kk = 0; kk < 4; ++kk) {
                int cidx = kk * 4 + lg;
                f16x8 vl = *reinterpret_cast<const f16x8*>(&tT[(cbL + cidx) << 2]);
                f16x8 vr = *reinterpret_cast<const f16x8*>(&tT[(cbR + cidx) << 2]);
                hA[kk] = hA[kk] + vl * wl8 + vr * w8;
            }
        }
        f16x8 z8 = (f16x8){0, 0, 0, 0, 0, 0, 0, 0};
#pragma unroll
        for (int kk = 0; kk < 4; ++kk)
            hA[kk] = __builtin_elementwise_max(hA[kk], z8);

        // Layer 1: 8 N-tiles x 4 K-steps, B straight from registers
        f32x4 acc[8];
#pragma unroll
        for (int nt = 0; nt < 8; ++nt) acc[nt] = (f32x4){0.f, 0.f, 0.f, 0.f};

#pragma unroll
        for (int kk = 0; kk < 4; ++kk) {
#pragma unroll
            for (int nt = 0; nt < 8; ++nt) {
                acc[nt] = __builtin_amdgcn_mfma_f32_16x16x32_f16(
                    hA[kk], __builtin_bit_cast(f16x8, Bf[kk][nt]), acc[nt],
                    0, 0, 0);
            }
        }

        // Layer 2 + bias/relu epilogue. acc[nt][i] = h1pre[m=lg*4+i][n=nt*16+lp]
        float part0 = 0.f, part1 = 0.f, part2 = 0.f, part3 = 0.f;
#pragma unroll
        for (int nt = 0; nt < 8; ++nt) {
            part0 += w2r[nt] * fmaxf(acc[nt][0] + b1r[nt], 0.f);
            part1 += w2r[nt] * fmaxf(acc[nt][1] + b1r[nt], 0.f);
            part2 += w2r[nt] * fmaxf(acc[nt][2] + b1r[nt], 0.f);
            part3 += w2r[nt] * fmaxf(acc[nt][3] + b1r[nt], 0.f);
        }
        // reduce over the 16-lane DPP row (channels) via rotation-adds (VALU)
        part0 = dpp_ror_add<0x128>(part0);  // ROW_ROR:8
        part1 = dpp_ror_add<0x128>(part1);
        part2 = dpp_ror_add<0x128>(part2);
        part3 = dpp_ror_add<0x128>(part3);
        part0 = dpp_ror_add<0x124>(part0);  // ROW_ROR:4
        part1 = dpp_ror_add<0x124>(part1);
        part2 = dpp_ror_add<0x124>(part2);
        part3 = dpp_ror_add<0x124>(part3);
        part0 = dpp_ror_add<0x122>(part0);  // ROW_ROR:2
        part1 = dpp_ror_add<0x122>(part1);
        part2 = dpp_ror_add<0x122>(part2);
        part3 = dpp_ror_add<0x122>(part3);
        part0 = dpp_ror_add<0x121>(part0);  // ROW_ROR:1
        part1 = dpp_ror_add<0x121>(part1);
        part2 = dpp_ror_add<0x121>(part2);
        part3 = dpp_ror_add<0x121>(part3);

        int mbase = m0 + (lg << 2);
        if (lp == 0 && mbase + 0 < npts) out[mbase + 0] = part0 + b2;
        if (lp == 1 && mbase + 1 < npts) out[mbase + 1] = part1 + b2;
        if (lp == 2 && mbase + 2 < npts) out[mbase + 2] = part2 + b2;
        if (lp == 3 && mbase + 3 < npts) out[mbase + 3] = part3 + b2;
    }
}

extern "C" void kernel_launch(void* const* d_in, const int* in_sizes, int n_in,
                              void* d_out, int out_size, void* d_ws, size_t ws_size,
                              hipStream_t stream) {
    const float* expr = (const float*)d_in[0];
    const float* jqw  = (const float*)d_in[1];
    const float* xyz  = (const float*)d_in[2];
    const float* flx  = (const float*)d_in[3];
    const float* fly  = (const float*)d_in[4];
    const float* flz  = (const float*)d_in[5];
    const float* w0v  = (const float*)d_in[6];
    const float* w0g  = (const float*)d_in[7];
    const float* b0   = (const float*)d_in[8];
    const float* w1v  = (const float*)d_in[9];
    const float* w1g  = (const float*)d_in[10];
    const float* b1   = (const float*)d_in[11];
    const float* w2v  = (const float*)d_in[12];
    const float* w2g  = (const float*)d_in[13];
    const float* b2   = (const float*)d_in[14];

    float* ws = (float*)d_ws;
    float* T       = ws;            // 24576 floats
    float* w0scale = ws + 24576;    // 128
    float* w2n     = ws + 24704;    // 128
    h2*    Wf      = (h2*)(ws + 24832);  // 8192 h2

    int npts = in_sizes[2] / 3;

    precompute_ws<<<1, 512, 0, stream>>>(w0v, w0g, w1v, w1g, w2v, w2g,
                                         w0scale, w2n, Wf);
    precompute_T<<<192, 128, 0, stream>>>(expr, jqw, flx, fly, flz, w0v,
                                          w0scale, b0, T);
    mlp_mfma<<<256, 512, 0, stream>>>(xyz, T, (const f32x4*)Wf, w2n, b1, b2,
                                      (float*)d_out, npts);
}